// Round 4
// baseline (277.244 us; speedup 1.0000x reference)
//
#include <hip/hip_runtime.h>
#include <hip/hip_bf16.h>

#define B_ 32
#define T_ 256
#define D_ 64
#define H_ 128
#define G_ 384   // 3*H

typedef _Float16 half8 __attribute__((ext_vector_type(8)));
typedef _Float16 half4v __attribute__((ext_vector_type(4)));
typedef _Float16 half2v __attribute__((ext_vector_type(2)));
typedef float float4v __attribute__((ext_vector_type(4)));

__device__ __forceinline__ float fsigmoid(float x){ return 1.0f/(1.0f+__expf(-x)); }
__device__ __forceinline__ float ftanh_(float x){ return 1.0f - 2.0f/(1.0f+__expf(2.0f*x)); }

// NOTE (R5-R7 post-mortem): inputs/outputs are f32. bf16 misread was the NaN bug.
//
// Structure ledger (measured):
//  - v10 (R10): 1-barrier 4-wave chained-MFMA step = 1241 cyc/step (132.4 us).
//    96 MFMAs/step (mat-vec, 15/16 M-rows wasted) = ~466 cyc CU-serial issue
//    floor. VGPR 140 resident OK.
//  - v11 (R12): fdot2 pair(xor1), 96 weight regs = 150.5 us. VGPR 124.
//  - v12 (R13): fdot2 k-split(xor32), 96 weight regs = 141 us. VGPR 108: the
//    allocator REMATTED the weight loads into the loop (~660 VALU cyc/step).
//  - v13 (R14): v12 + anti-remat pins = 163.4 us, VGPR 96: pins forced scratch
//    SPILL instead. Verdict: allocator will not hold ~96 weight VGPRs in this
//    loop, full stop. Comfort band is <~110 total.
//  - v14 (R15, this): 8 waves, k-quartered fdot2 -> 48 weight VGPRs/lane
//    (static need ~100, inside comfort band). Per-SIMD issue unchanged
//    (2 waves x 48 = 192 cyc). 2-level shfl_xor(16/32) combine; gates on
//    kq==0 lanes. Same 1-BAR/step skeleton. No pins.
#define BAR() do{ asm volatile("s_waitcnt lgkmcnt(0)" ::: "memory"); \
                  __builtin_amdgcn_s_barrier(); \
                  asm volatile("" ::: "memory"); } while(0)

// wcol[b,j] = column sums of the row-normalized adjacency (R1 derivation):
// adj_raw[i,j] = p_i p_j sim_ij + I; rs_i = 1 + p_i*sum_j p_j sim_ij;
// wcol_j = p_j * sum_i p_i sim_ij / rs_i + 1/rs_j  (sim symmetric).
__global__ void __launch_bounds__(256) adj_k(const float* mm, const float* E,
                                             float* wcol){
  int b = blockIdx.x;
  int tid = threadIdx.x;
  int d = tid & 63, q = tid >> 6;
  __shared__ float spp[4][64];
  __shared__ float sp[64];
  __shared__ float sE[64*129];
  __shared__ float ssim[64*65];
  __shared__ float srs[64];
  float p = 0.0f;
  for (int t = q*64; t < q*64+64; t++) p += 1.0f - mm[(b*T_ + t)*D_ + d];
  spp[q][d] = p;
  for (int i = tid; i < D_*H_; i += 256){ int r = i >> 7, c = i & 127; sE[r*129+c] = E[i]; }
  __syncthreads();
  if (tid < 64) sp[tid] = (spp[0][tid]+spp[1][tid]+spp[2][tid]+spp[3][tid]) * (1.0f/T_);
  __syncthreads();
  float rowE[128];
  #pragma unroll
  for (int k = 0; k < 128; k++) rowE[k] = sE[d*129+k];
  for (int i = q*16; i < q*16+16; i++){
    float s = 0.0f;
    #pragma unroll
    for (int k = 0; k < 128; k++) s += rowE[k]*sE[i*129+k];
    ssim[d*65+i] = fmaxf(s, 0.0f);
  }
  __syncthreads();
  if (tid < 64){
    float rs = 0.0f;
    for (int j = 0; j < 64; j++) rs += sp[j]*ssim[tid*65+j];
    srs[tid] = fmaxf(sp[tid]*rs + 1.0f, 1e-6f);
  }
  __syncthreads();
  if (tid < 64){
    float s = 0.0f;
    for (int i = 0; i < 64; i++) s += sp[i]*ssim[tid*65+i]/srs[i];
    wcol[b*64 + tid] = sp[tid]*s + 1.0f/srs[tid];
  }
}

// gi_k v5: gi3 f16 (halves gi traffic); E staged into LDS f16 (pitch 132).
// Phase A: vr[32t][128h] = (x*(1-mm)*wcol/64)[32t][64d] x E[64d][128h] + time-enc
// Phase B: gi[32t][384g] = vr x W_ih^T + (bih + bhh[r,z]); gi3 transposed [b][g][t].
#define AVP 72
#define VRP 136
#define SEP 132
__global__ void __launch_bounds__(512,1) gi_k(const float* x, const float* mm,
                                              const float* vt, const float* E,
                                              const float* wih, const float* bih,
                                              const float* bhh, const float* wcol,
                                              _Float16* gi3){
  int bid = blockIdx.x;
  int b = bid >> 3, t0 = (bid & 7)*32;
  int tid = threadIdx.x;
  int w = tid >> 6, l = tid & 63;
  int lq = l >> 4, lm = l & 15;

  __shared__ __align__(16) _Float16 av[32*AVP];
  __shared__ __align__(16) _Float16 vrA[32*VRP];
  __shared__ __align__(16) _Float16 sEl[64*SEP];
  __shared__ float sVt[32];

  // stage av[t][d] = x*(1-mm)*wcol/64  (f32 in, f16 out)
  {
    int i = tid*4, t = i >> 6, d4 = i & 63;
    long src = (long)(b*T_ + t0 + t)*D_ + d4;
    float4 xv = *(const float4*)&x[src];
    float4 mv = *(const float4*)&mm[src];
    float4 wv = *(const float4*)&wcol[b*D_ + d4];
    half4v h;
    h[0]=(_Float16)(xv.x*(1.0f-mv.x)*wv.x*(1.0f/64));
    h[1]=(_Float16)(xv.y*(1.0f-mv.y)*wv.y*(1.0f/64));
    h[2]=(_Float16)(xv.z*(1.0f-mv.z)*wv.z*(1.0f/64));
    h[3]=(_Float16)(xv.w*(1.0f-mv.w)*wv.w*(1.0f/64));
    *(half4v*)&av[t*AVP + d4] = h;
  }
  // stage E -> LDS f16, coalesced
  {
    int r = tid >> 3, c0 = (tid & 7)*16;
    #pragma unroll
    for (int g = 0; g < 4; g++){
      float4 v = *(const float4*)&E[r*H_ + c0 + g*4];
      half4v h;
      h[0]=(_Float16)v.x; h[1]=(_Float16)v.y; h[2]=(_Float16)v.z; h[3]=(_Float16)v.w;
      *(half4v*)&sEl[r*SEP + c0 + g*4] = h;
    }
  }
  if (tid < 32) sVt[tid] = vt[b*T_ + t0 + tid];
  __syncthreads();

  // Phase A B-frags: B[k=d][n] = E[d][16w+n]  (gather from LDS)
  half8 bE[2];
  #pragma unroll
  for (int kc = 0; kc < 2; kc++){
    half8 f;
    #pragma unroll
    for (int jj = 0; jj < 8; jj++)
      f[jj] = sEl[(kc*32 + lq*8 + jj)*SEP + 16*w + lm];
    bE[kc] = f;
  }

  float4v accA[2] = {{0,0,0,0},{0,0,0,0}};
  #pragma unroll
  for (int kc = 0; kc < 2; kc++){
    #pragma unroll
    for (int mt = 0; mt < 2; mt++){
      half8 a = *(const half8*)&av[(mt*16+lm)*AVP + kc*32 + lq*8];
      accA[mt] = __builtin_amdgcn_mfma_f32_16x16x32_f16(a, bE[kc], accA[mt], 0,0,0);
    }
  }
  {
    int h = 16*w + lm;
    float fr = __expf(-(float)(h & 63) * 0.14391157f);   // ln(1e4)/64
    #pragma unroll
    for (int mt = 0; mt < 2; mt++){
      #pragma unroll
      for (int r = 0; r < 4; r++){
        int tl = mt*16 + lq*4 + r;
        float ang = sVt[tl] * fr;
        float e = (h < 64) ? __sinf(ang) : __cosf(ang);
        vrA[tl*VRP + h] = (_Float16)(accA[mt][r] + e);
      }
    }
  }
  __syncthreads();

  // Phase B: wave owns N-tiles 3w..3w+2
  half8 bW[3][4]; float biW[3];
  #pragma unroll
  for (int q = 0; q < 3; q++){
    int g = 16*(3*w + q) + lm;
    biW[q] = bih[g] + (g < 2*H_ ? bhh[g] : 0.0f);  // fold b_hh for r,z
    #pragma unroll
    for (int kc = 0; kc < 4; kc++){
      const float* src = &wih[(long)g*H_ + kc*32 + lq*8];
      float4 x0 = *(const float4*)src;
      float4 x1 = *(const float4*)(src+4);
      half8 f;
      f[0]=(_Float16)x0.x; f[1]=(_Float16)x0.y; f[2]=(_Float16)x0.z; f[3]=(_Float16)x0.w;
      f[4]=(_Float16)x1.x; f[5]=(_Float16)x1.y; f[6]=(_Float16)x1.z; f[7]=(_Float16)x1.w;
      bW[q][kc] = f;
    }
  }
  float4v cB[2][3];
  #pragma unroll
  for (int mt = 0; mt < 2; mt++)
    #pragma unroll
    for (int q = 0; q < 3; q++) cB[mt][q] = (float4v){0,0,0,0};
  #pragma unroll
  for (int kc = 0; kc < 4; kc++){
    #pragma unroll
    for (int mt = 0; mt < 2; mt++){
      half8 a = *(const half8*)&vrA[(mt*16+lm)*VRP + kc*32 + lq*8];
      #pragma unroll
      for (int q = 0; q < 3; q++)
        cB[mt][q] = __builtin_amdgcn_mfma_f32_16x16x32_f16(a, bW[q][kc], cB[mt][q], 0,0,0);
    }
  }
  #pragma unroll
  for (int mt = 0; mt < 2; mt++){
    #pragma unroll
    for (int q = 0; q < 3; q++){
      int g = 16*(3*w + q) + lm;
      int tb = t0 + mt*16 + lq*4;
      half4v hv;
      hv[0]=(_Float16)(cB[mt][q][0] + biW[q]); hv[1]=(_Float16)(cB[mt][q][1] + biW[q]);
      hv[2]=(_Float16)(cB[mt][q][2] + biW[q]); hv[3]=(_Float16)(cB[mt][q][3] + biW[q]);
      *(half4v*)&gi3[((long)(b*G_ + g))*T_ + tb] = hv;
    }
  }
}

// Sequential GRU v14 (R15): 8-wave k-quartered fdot2.
// Lane (w, l): j = 16w + (l&15), kq = l>>4. Lane reduces k in
// [kq*32, kq*32+32) for all three gates = 48 fdot2/lane/step, 48 weight
// VGPRs (under the allocator's ~110 comfort band; v12/v13 proved 96 gets
// rematted/spilled). Per-SIMD issue: 2 waves x 48 = 192 cyc. Combine via
// shfl_xor(16)+shfl_xor(32); gate math + h/out writes on kq==0 lanes.
// One LDS-only BAR per step, hb[2] f16 ping-pong, named A/B gi prefetch.
__global__ void __launch_bounds__(512,1) gru_k(const _Float16* gi3, const float* whh,
                                               const float* bhh, const int* lengths,
                                               float* out){
  int b = blockIdx.x;
  int tid = threadIdx.x;
  int w = tid >> 6, l = tid & 63;
  int kq = l >> 4;                 // k-quarter 0..3
  int j  = 16*w + (l & 15);        // gate row owned by the 4-lane group
  bool g0 = (kq == 0);
  int len = lengths[b];

  __shared__ __align__(16) _Float16 hb[2][H_];

  // Weights: rows {j, H+j, 2H+j}, k in [kq*32, kq*32+32) -> 16 half2 each.
  half2v Wr[16], Wz[16], Wn[16];
  {
    const float* baseR = &whh[(long)j*H_        + kq*32];
    const float* baseZ = &whh[(long)(H_ + j)*H_ + kq*32];
    const float* baseN = &whh[(long)(2*H_+j)*H_ + kq*32];
    #pragma unroll
    for (int t4 = 0; t4 < 8; t4++){
      float4 vr = *(const float4*)(baseR + t4*4);
      float4 vz = *(const float4*)(baseZ + t4*4);
      float4 vn = *(const float4*)(baseN + t4*4);
      half2v a;
      a[0]=(_Float16)vr.x; a[1]=(_Float16)vr.y; Wr[2*t4] = a;
      a[0]=(_Float16)vr.z; a[1]=(_Float16)vr.w; Wr[2*t4+1] = a;
      a[0]=(_Float16)vz.x; a[1]=(_Float16)vz.y; Wz[2*t4] = a;
      a[0]=(_Float16)vz.z; a[1]=(_Float16)vz.w; Wz[2*t4+1] = a;
      a[0]=(_Float16)vn.x; a[1]=(_Float16)vn.y; Wn[2*t4] = a;
      a[0]=(_Float16)vn.z; a[1]=(_Float16)vn.w; Wn[2*t4+1] = a;
    }
  }
  float bn_ = bhh[2*H_ + j];
  const _Float16* pr = gi3 + ((long)b*G_ + j)*T_;
  const _Float16* pz = pr + (long)H_*T_;
  const _Float16* pn = pr + (long)2*H_*T_;

  if (tid < H_){ hb[0][tid] = (_Float16)0.0f; hb[1][tid] = (_Float16)0.0f; }

  // gi prefetch: named double-buffer registers, static (no runtime indexing)
  half8 prA, pzA, pnA, prB, pzB, pnB;
  if (g0){
    prA = *(const half8*)pr; pzA = *(const half8*)pz; pnA = *(const half8*)pn;
  }
  __syncthreads();

  float hval = 0.0f;

  auto substeps = [&](half8 cr, half8 cz, half8 cn, int c){
    #pragma unroll
    for (int i = 0; i < 8; i++){
      const int rp = i & 1;            // read hb[rp], write hb[rp^1]
      float ar0=0.0f, ar1=0.0f, az0=0.0f, az1=0.0f, an0=0.0f, an1=0.0f;
      #pragma unroll
      for (int q8 = 0; q8 < 4; q8++){
        half8 hv = *(const half8*)&hb[rp][kq*32 + q8*8];   // 4 addrs/wave, broadcast
        #pragma unroll
        for (int m = 0; m < 4; m++){
          half2v h2; h2[0] = hv[2*m]; h2[1] = hv[2*m+1];
          const int q = q8*4 + m;
          if ((q & 1) == 0){
            ar0 = __builtin_amdgcn_fdot2(h2, Wr[q], ar0, false);
            az0 = __builtin_amdgcn_fdot2(h2, Wz[q], az0, false);
            an0 = __builtin_amdgcn_fdot2(h2, Wn[q], an0, false);
          } else {
            ar1 = __builtin_amdgcn_fdot2(h2, Wr[q], ar1, false);
            az1 = __builtin_amdgcn_fdot2(h2, Wz[q], az1, false);
            an1 = __builtin_amdgcn_fdot2(h2, Wn[q], an1, false);
          }
        }
      }
      float R = ar0 + ar1, Z = az0 + az1, N = an0 + an1;
      R += __shfl_xor(R, 16, 64);      // kq0<->kq1, kq2<->kq3
      Z += __shfl_xor(Z, 16, 64);
      N += __shfl_xor(N, 16, 64);
      R += __shfl_xor(R, 32, 64);      // fold upper pair into lower
      Z += __shfl_xor(Z, 32, 64);
      N += __shfl_xor(N, 32, 64);
      if (g0){
        float r = fsigmoid((float)cr[i] + R);
        float z = fsigmoid((float)cz[i] + Z);
        float n = ftanh_((float)cn[i] + r*(N + bn_));
        hval = (1.0f - z)*n + z*hval;
        hb[rp^1][j] = (_Float16)hval;
        int t = c*8 + i;
        out[((long)(b*T_ + t))*H_ + j] = (t < len) ? hval : 0.0f;
      }
      BAR();
    }
  };

  for (int c = 0; c < 32; c += 2){
    if (g0){
      int nb = (c+1)*8;
      prB = *(const half8*)(pr+nb); pzB = *(const half8*)(pz+nb); pnB = *(const half8*)(pn+nb);
    }
    substeps(prA, pzA, pnA, c);
    if (g0 && c+2 < 32){
      int nb = (c+2)*8;
      prA = *(const half8*)(pr+nb); pzA = *(const half8*)(pz+nb); pnA = *(const half8*)(pn+nb);
    }
    substeps(prB, pzB, pnB, c+1);
  }
}

extern "C" void kernel_launch(void* const* d_in, const int* in_sizes, int n_in,
                              void* d_out, int out_size, void* d_ws, size_t ws_size,
                              hipStream_t stream) {
  char* base = (char*)d_ws;
  size_t off = 0;
  auto alloc = [&](size_t bytes)->void*{
    void* p = base + off; off = (off + bytes + 255) & ~(size_t)255; return p;
  };
  float*     wcol = (float*)alloc((size_t)B_*D_*4);
  _Float16*  gi3  = (_Float16*)alloc((size_t)B_*G_*T_*2);
  if (off > ws_size) return;

  const float* x   = (const float*)d_in[0];
  const float* mm  = (const float*)d_in[1];
  const float* vt  = (const float*)d_in[2];
  const int*   len = (const int*)d_in[4];
  const float* E   = (const float*)d_in[5];
  const float* wih = (const float*)d_in[6];
  const float* whh = (const float*)d_in[7];
  const float* bih = (const float*)d_in[8];
  const float* bhh = (const float*)d_in[9];

  adj_k<<<dim3(B_),dim3(256),0,stream>>>(mm, E, wcol);
  gi_k<<<dim3(256),dim3(512),0,stream>>>(x, mm, vt, E, wih, bih, bhh, wcol, gi3);
  gru_k<<<dim3(B_),dim3(512),0,stream>>>(gi3, whh, bhh, len, (float*)d_out);
}

// Round 5
// 262.268 us; speedup vs baseline: 1.0571x; 1.0571x over previous
//
#include <hip/hip_runtime.h>
#include <hip/hip_bf16.h>

#define B_ 32
#define T_ 256
#define D_ 64
#define H_ 128
#define G_ 384   // 3*H

typedef _Float16 half8 __attribute__((ext_vector_type(8)));
typedef _Float16 half4v __attribute__((ext_vector_type(4)));
typedef _Float16 half2v __attribute__((ext_vector_type(2)));
typedef float float4v __attribute__((ext_vector_type(4)));

__device__ __forceinline__ float fsigmoid(float x){ return 1.0f/(1.0f+__expf(-x)); }
__device__ __forceinline__ float ftanh_(float x){ return 1.0f - 2.0f/(1.0f+__expf(2.0f*x)); }

// NOTE (R5-R7 post-mortem): inputs/outputs are f32. bf16 misread was the NaN bug.
//
// Structure ledger (measured):
//  - v10 (R10): 1-barrier 4-wave chained-MFMA step = 1241 cyc/step (132.4 us).
//    96 MFMAs/step (mat-vec, 15/16 M-rows wasted) = ~466 cyc CU-serial issue
//    floor. VGPR 140 resident OK.
//  - v11 (R12): fdot2 pair(xor1), 96 weight regs = 150.5 us. VGPR 124.
//  - v12 (R13): fdot2 k-split(xor32), 96 weight regs = 141 us. VGPR 108:
//    whh loads are invariant -> allocator rematted them into the loop.
//  - v13 (R14): v12 + anti-remat pins = 163.4 us, VGPR 96: scratch spill.
//  - v14 (R15): 8 waves, 48 wregs, ~100 static = 157 us, VGPR 60: STILL
//    rematted. Conclusion: not a capacity issue — the backend's occupancy
//    heuristic hands the allocator a tight budget (launch_bounds only sets
//    the MIN waves/EU; scheduler targets more).
//  - v15 (R16, this): v12 + amdgpu_waves_per_eu(1,1) — truthful clamp
//    (32 blocks x 4 waves = 1 wave/EU) that lifts the VGPR budget to 512.
//    Verdict bit: VGPR_Count >= 150. If it stays <= 110, fdot2 line is dead;
//    fallback = v10 MFMA or batched-M GEMM restructure.
#define BAR() do{ asm volatile("s_waitcnt lgkmcnt(0)" ::: "memory"); \
                  __builtin_amdgcn_s_barrier(); \
                  asm volatile("" ::: "memory"); } while(0)

// wcol[b,j] = column sums of the row-normalized adjacency (R1 derivation):
// adj_raw[i,j] = p_i p_j sim_ij + I; rs_i = 1 + p_i*sum_j p_j sim_ij;
// wcol_j = p_j * sum_i p_i sim_ij / rs_i + 1/rs_j  (sim symmetric).
__global__ void __launch_bounds__(256) adj_k(const float* mm, const float* E,
                                             float* wcol){
  int b = blockIdx.x;
  int tid = threadIdx.x;
  int d = tid & 63, q = tid >> 6;
  __shared__ float spp[4][64];
  __shared__ float sp[64];
  __shared__ float sE[64*129];
  __shared__ float ssim[64*65];
  __shared__ float srs[64];
  float p = 0.0f;
  for (int t = q*64; t < q*64+64; t++) p += 1.0f - mm[(b*T_ + t)*D_ + d];
  spp[q][d] = p;
  for (int i = tid; i < D_*H_; i += 256){ int r = i >> 7, c = i & 127; sE[r*129+c] = E[i]; }
  __syncthreads();
  if (tid < 64) sp[tid] = (spp[0][tid]+spp[1][tid]+spp[2][tid]+spp[3][tid]) * (1.0f/T_);
  __syncthreads();
  float rowE[128];
  #pragma unroll
  for (int k = 0; k < 128; k++) rowE[k] = sE[d*129+k];
  for (int i = q*16; i < q*16+16; i++){
    float s = 0.0f;
    #pragma unroll
    for (int k = 0; k < 128; k++) s += rowE[k]*sE[i*129+k];
    ssim[d*65+i] = fmaxf(s, 0.0f);
  }
  __syncthreads();
  if (tid < 64){
    float rs = 0.0f;
    for (int j = 0; j < 64; j++) rs += sp[j]*ssim[tid*65+j];
    srs[tid] = fmaxf(sp[tid]*rs + 1.0f, 1e-6f);
  }
  __syncthreads();
  if (tid < 64){
    float s = 0.0f;
    for (int i = 0; i < 64; i++) s += sp[i]*ssim[tid*65+i]/srs[i];
    wcol[b*64 + tid] = sp[tid]*s + 1.0f/srs[tid];
  }
}

// gi_k v5: gi3 f16 (halves gi traffic); E staged into LDS f16 (pitch 132).
// Phase A: vr[32t][128h] = (x*(1-mm)*wcol/64)[32t][64d] x E[64d][128h] + time-enc
// Phase B: gi[32t][384g] = vr x W_ih^T + (bih + bhh[r,z]); gi3 transposed [b][g][t].
#define AVP 72
#define VRP 136
#define SEP 132
__global__ void __launch_bounds__(512,1) gi_k(const float* x, const float* mm,
                                              const float* vt, const float* E,
                                              const float* wih, const float* bih,
                                              const float* bhh, const float* wcol,
                                              _Float16* gi3){
  int bid = blockIdx.x;
  int b = bid >> 3, t0 = (bid & 7)*32;
  int tid = threadIdx.x;
  int w = tid >> 6, l = tid & 63;
  int lq = l >> 4, lm = l & 15;

  __shared__ __align__(16) _Float16 av[32*AVP];
  __shared__ __align__(16) _Float16 vrA[32*VRP];
  __shared__ __align__(16) _Float16 sEl[64*SEP];
  __shared__ float sVt[32];

  // stage av[t][d] = x*(1-mm)*wcol/64  (f32 in, f16 out)
  {
    int i = tid*4, t = i >> 6, d4 = i & 63;
    long src = (long)(b*T_ + t0 + t)*D_ + d4;
    float4 xv = *(const float4*)&x[src];
    float4 mv = *(const float4*)&mm[src];
    float4 wv = *(const float4*)&wcol[b*D_ + d4];
    half4v h;
    h[0]=(_Float16)(xv.x*(1.0f-mv.x)*wv.x*(1.0f/64));
    h[1]=(_Float16)(xv.y*(1.0f-mv.y)*wv.y*(1.0f/64));
    h[2]=(_Float16)(xv.z*(1.0f-mv.z)*wv.z*(1.0f/64));
    h[3]=(_Float16)(xv.w*(1.0f-mv.w)*wv.w*(1.0f/64));
    *(half4v*)&av[t*AVP + d4] = h;
  }
  // stage E -> LDS f16, coalesced
  {
    int r = tid >> 3, c0 = (tid & 7)*16;
    #pragma unroll
    for (int g = 0; g < 4; g++){
      float4 v = *(const float4*)&E[r*H_ + c0 + g*4];
      half4v h;
      h[0]=(_Float16)v.x; h[1]=(_Float16)v.y; h[2]=(_Float16)v.z; h[3]=(_Float16)v.w;
      *(half4v*)&sEl[r*SEP + c0 + g*4] = h;
    }
  }
  if (tid < 32) sVt[tid] = vt[b*T_ + t0 + tid];
  __syncthreads();

  // Phase A B-frags: B[k=d][n] = E[d][16w+n]  (gather from LDS)
  half8 bE[2];
  #pragma unroll
  for (int kc = 0; kc < 2; kc++){
    half8 f;
    #pragma unroll
    for (int jj = 0; jj < 8; jj++)
      f[jj] = sEl[(kc*32 + lq*8 + jj)*SEP + 16*w + lm];
    bE[kc] = f;
  }

  float4v accA[2] = {{0,0,0,0},{0,0,0,0}};
  #pragma unroll
  for (int kc = 0; kc < 2; kc++){
    #pragma unroll
    for (int mt = 0; mt < 2; mt++){
      half8 a = *(const half8*)&av[(mt*16+lm)*AVP + kc*32 + lq*8];
      accA[mt] = __builtin_amdgcn_mfma_f32_16x16x32_f16(a, bE[kc], accA[mt], 0,0,0);
    }
  }
  {
    int h = 16*w + lm;
    float fr = __expf(-(float)(h & 63) * 0.14391157f);   // ln(1e4)/64
    #pragma unroll
    for (int mt = 0; mt < 2; mt++){
      #pragma unroll
      for (int r = 0; r < 4; r++){
        int tl = mt*16 + lq*4 + r;
        float ang = sVt[tl] * fr;
        float e = (h < 64) ? __sinf(ang) : __cosf(ang);
        vrA[tl*VRP + h] = (_Float16)(accA[mt][r] + e);
      }
    }
  }
  __syncthreads();

  // Phase B: wave owns N-tiles 3w..3w+2
  half8 bW[3][4]; float biW[3];
  #pragma unroll
  for (int q = 0; q < 3; q++){
    int g = 16*(3*w + q) + lm;
    biW[q] = bih[g] + (g < 2*H_ ? bhh[g] : 0.0f);  // fold b_hh for r,z
    #pragma unroll
    for (int kc = 0; kc < 4; kc++){
      const float* src = &wih[(long)g*H_ + kc*32 + lq*8];
      float4 x0 = *(const float4*)src;
      float4 x1 = *(const float4*)(src+4);
      half8 f;
      f[0]=(_Float16)x0.x; f[1]=(_Float16)x0.y; f[2]=(_Float16)x0.z; f[3]=(_Float16)x0.w;
      f[4]=(_Float16)x1.x; f[5]=(_Float16)x1.y; f[6]=(_Float16)x1.z; f[7]=(_Float16)x1.w;
      bW[q][kc] = f;
    }
  }
  float4v cB[2][3];
  #pragma unroll
  for (int mt = 0; mt < 2; mt++)
    #pragma unroll
    for (int q = 0; q < 3; q++) cB[mt][q] = (float4v){0,0,0,0};
  #pragma unroll
  for (int kc = 0; kc < 4; kc++){
    #pragma unroll
    for (int mt = 0; mt < 2; mt++){
      half8 a = *(const half8*)&vrA[(mt*16+lm)*VRP + kc*32 + lq*8];
      #pragma unroll
      for (int q = 0; q < 3; q++)
        cB[mt][q] = __builtin_amdgcn_mfma_f32_16x16x32_f16(a, bW[q][kc], cB[mt][q], 0,0,0);
    }
  }
  #pragma unroll
  for (int mt = 0; mt < 2; mt++){
    #pragma unroll
    for (int q = 0; q < 3; q++){
      int g = 16*(3*w + q) + lm;
      int tb = t0 + mt*16 + lq*4;
      half4v hv;
      hv[0]=(_Float16)(cB[mt][q][0] + biW[q]); hv[1]=(_Float16)(cB[mt][q][1] + biW[q]);
      hv[2]=(_Float16)(cB[mt][q][2] + biW[q]); hv[3]=(_Float16)(cB[mt][q][3] + biW[q]);
      *(half4v*)&gi3[((long)(b*G_ + g))*T_ + tb] = hv;
    }
  }
}

// Sequential GRU v15 (R16): v12 k-split fdot2 + amdgpu_waves_per_eu(1,1).
// Lane l and l+32 of wave w co-own gate row j = 32w + (l&31): lane reduces
// k in [kh*64, kh*64+64) for all three gates (96 fdot2/lane). Pair-combine
// via 3x shfl_xor(32); gate math + h write on kh==0. One LDS-only BAR per
// step, hb[2] f16 ping-pong, named A/B gi prefetch. The waves_per_eu(1,1)
// clamp (truthful: 1 wave/EU at this launch shape) lifts the allocator's
// occupancy-driven VGPR budget so the 96 weight regs stay resident instead
// of being rematerialized from L2 per use (v12/v13/v14 failure mode).
__global__ void __attribute__((amdgpu_waves_per_eu(1, 1)))
__launch_bounds__(256) gru_k(const _Float16* gi3, const float* whh,
                             const float* bhh, const int* lengths,
                             float* out){
  int b = blockIdx.x;
  int tid = threadIdx.x;
  int w = tid >> 6, l = tid & 63;
  int kh = l >> 5;               // this lane's k-half
  int j  = 32*w + (l & 31);      // gate row owned by the (l, l+32) pair
  bool lo = (kh == 0);
  int len = lengths[b];

  __shared__ __align__(16) _Float16 hb[2][H_];

  // Weights in registers: rows {j, H+j, 2H+j}, k in [kh*64, kh*64+64)
  half2v Wr[32], Wz[32], Wn[32];
  {
    const float* baseR = &whh[(long)j*H_        + kh*64];
    const float* baseZ = &whh[(long)(H_ + j)*H_ + kh*64];
    const float* baseN = &whh[(long)(2*H_+j)*H_ + kh*64];
    #pragma unroll
    for (int t4 = 0; t4 < 16; t4++){
      float4 vr = *(const float4*)(baseR + t4*4);
      float4 vz = *(const float4*)(baseZ + t4*4);
      float4 vn = *(const float4*)(baseN + t4*4);
      half2v a;
      a[0]=(_Float16)vr.x; a[1]=(_Float16)vr.y; Wr[2*t4] = a;
      a[0]=(_Float16)vr.z; a[1]=(_Float16)vr.w; Wr[2*t4+1] = a;
      a[0]=(_Float16)vz.x; a[1]=(_Float16)vz.y; Wz[2*t4] = a;
      a[0]=(_Float16)vz.z; a[1]=(_Float16)vz.w; Wz[2*t4+1] = a;
      a[0]=(_Float16)vn.x; a[1]=(_Float16)vn.y; Wn[2*t4] = a;
      a[0]=(_Float16)vn.z; a[1]=(_Float16)vn.w; Wn[2*t4+1] = a;
    }
  }
  float bn_ = bhh[2*H_ + j];
  const _Float16* pr = gi3 + ((long)b*G_ + j)*T_;
  const _Float16* pz = pr + (long)H_*T_;
  const _Float16* pn = pr + (long)2*H_*T_;

  if (tid < H_){ hb[0][tid] = (_Float16)0.0f; hb[1][tid] = (_Float16)0.0f; }

  // gi prefetch: named double-buffer registers, static (no runtime indexing)
  half8 prA, pzA, pnA, prB, pzB, pnB;
  if (lo){
    prA = *(const half8*)pr; pzA = *(const half8*)pz; pnA = *(const half8*)pn;
  }
  __syncthreads();   // cold path: full barrier fine

  float hval = 0.0f;

  auto substeps = [&](half8 cr, half8 cz, half8 cn, int c){
    #pragma unroll
    for (int i = 0; i < 8; i++){
      const int rp = i & 1;            // read hb[rp], write hb[rp^1]
      float ar0=0.0f, ar1=0.0f, az0=0.0f, az1=0.0f, an0=0.0f, an1=0.0f;
      #pragma unroll
      for (int q8 = 0; q8 < 8; q8++){
        half8 hv = *(const half8*)&hb[rp][kh*64 + q8*8];   // 2 addrs/wave, broadcast
        #pragma unroll
        for (int m = 0; m < 4; m++){
          half2v h2; h2[0] = hv[2*m]; h2[1] = hv[2*m+1];
          const int q = q8*4 + m;
          if ((q & 1) == 0){
            ar0 = __builtin_amdgcn_fdot2(h2, Wr[q], ar0, false);
            az0 = __builtin_amdgcn_fdot2(h2, Wz[q], az0, false);
            an0 = __builtin_amdgcn_fdot2(h2, Wn[q], an0, false);
          } else {
            ar1 = __builtin_amdgcn_fdot2(h2, Wr[q], ar1, false);
            az1 = __builtin_amdgcn_fdot2(h2, Wz[q], az1, false);
            an1 = __builtin_amdgcn_fdot2(h2, Wn[q], an1, false);
          }
        }
      }
      float R = ar0 + ar1, Z = az0 + az1, N = an0 + an1;
      R += __shfl_xor(R, 32, 64);      // combine k-halves across the pair
      Z += __shfl_xor(Z, 32, 64);
      N += __shfl_xor(N, 32, 64);
      if (lo){
        float r = fsigmoid((float)cr[i] + R);
        float z = fsigmoid((float)cz[i] + Z);
        float n = ftanh_((float)cn[i] + r*(N + bn_));
        hval = (1.0f - z)*n + z*hval;
        hb[rp^1][j] = (_Float16)hval;
        int t = c*8 + i;
        out[((long)(b*T_ + t))*H_ + j] = (t < len) ? hval : 0.0f;
      }
      BAR();
    }
  };

  for (int c = 0; c < 32; c += 2){
    if (lo){
      int nb = (c+1)*8;
      prB = *(const half8*)(pr+nb); pzB = *(const half8*)(pz+nb); pnB = *(const half8*)(pn+nb);
    }
    substeps(prA, pzA, pnA, c);
    if (lo && c+2 < 32){
      int nb = (c+2)*8;
      prA = *(const half8*)(pr+nb); pzA = *(const half8*)(pz+nb); pnA = *(const half8*)(pn+nb);
    }
    substeps(prB, pzB, pnB, c+1);
  }
}

extern "C" void kernel_launch(void* const* d_in, const int* in_sizes, int n_in,
                              void* d_out, int out_size, void* d_ws, size_t ws_size,
                              hipStream_t stream) {
  char* base = (char*)d_ws;
  size_t off = 0;
  auto alloc = [&](size_t bytes)->void*{
    void* p = base + off; off = (off + bytes + 255) & ~(size_t)255; return p;
  };
  float*     wcol = (float*)alloc((size_t)B_*D_*4);
  _Float16*  gi3  = (_Float16*)alloc((size_t)B_*G_*T_*2);
  if (off > ws_size) return;

  const float* x   = (const float*)d_in[0];
  const float* mm  = (const float*)d_in[1];
  const float* vt  = (const float*)d_in[2];
  const int*   len = (const int*)d_in[4];
  const float* E   = (const float*)d_in[5];
  const float* wih = (const float*)d_in[6];
  const float* whh = (const float*)d_in[7];
  const float* bih = (const float*)d_in[8];
  const float* bhh = (const float*)d_in[9];

  adj_k<<<dim3(B_),dim3(256),0,stream>>>(mm, E, wcol);
  gi_k<<<dim3(256),dim3(512),0,stream>>>(x, mm, vt, E, wih, bih, bhh, wcol, gi3);
  gru_k<<<dim3(B_),dim3(256),0,stream>>>(gi3, whh, bhh, len, (float*)d_out);
}

// Round 6
// 238.651 us; speedup vs baseline: 1.1617x; 1.0990x over previous
//
#include <hip/hip_runtime.h>
#include <hip/hip_bf16.h>

#define B_ 32
#define T_ 256
#define D_ 64
#define H_ 128
#define G_ 384   // 3*H

typedef _Float16 half8 __attribute__((ext_vector_type(8)));
typedef _Float16 half4v __attribute__((ext_vector_type(4)));
typedef float float4v __attribute__((ext_vector_type(4)));

// Fast gate functions on PRE-SCALED inputs (log2e folded into weights/biases):
// s = log2e * x          -> sigmoid(x) = 1/(1+2^-s)
// t = 2*log2e * x        -> tanh(x)    = 1 - 2/(1+2^t)
// v_rcp_f32 (~1 ulp) replaces the f32 division sequence (v_div_scale/fmas/
// fixup ~40 cyc) that sat TWICE on the serial gate chain in v10.
__device__ __forceinline__ float fsigmoid2(float s){
  return __builtin_amdgcn_rcpf(1.0f + __builtin_amdgcn_exp2f(-s));
}
__device__ __forceinline__ float ftanh2(float t){
  return 1.0f - 2.0f*__builtin_amdgcn_rcpf(1.0f + __builtin_amdgcn_exp2f(t));
}
#define LOG2E  1.442695041f
#define LOG2E2 2.885390082f

// NOTE (R5-R7 post-mortem): inputs/outputs are f32. bf16 misread was the NaN bug.
//
// Structure ledger (measured):
//  - v10 (R10): 1-barrier 4-wave chained-MFMA step = 1241 cyc/step (132.4 us)
//    — champion. R4 8-wave +19us; R8 chain-split +13us; R11 2-barrier +11us
//    (=> marginal barrier ~13 cyc, NOT the bottleneck); R9 BAR flavor neutral.
//  - v11-v15 (R12-R16): fdot2 recurrence line. Best 139.4 us (v15, VGPR 132,
//    waves_per_eu(1,1)). Allocator never holds the 96 weight VGPRs resident
//    (remat at 108/60, scratch-spill when pinned at 96). LINE CLOSED.
//  - v16 (R17, this): v10 skeleton verbatim + gate-chain cut only:
//    v_rcp for both divisions + exp2 prefold (log2e into r/z rows, 2log2e
//    into n rows, applied at gi_k Phase-B and gru_k bfrag load — off the
//    critical path). Predicted -90..-140 cyc/substep.
#define BAR() do{ asm volatile("s_waitcnt lgkmcnt(0)" ::: "memory"); \
                  __builtin_amdgcn_s_barrier(); \
                  asm volatile("" ::: "memory"); } while(0)

// wcol[b,j] = column sums of the row-normalized adjacency (R1 derivation):
// adj_raw[i,j] = p_i p_j sim_ij + I; rs_i = 1 + p_i*sum_j p_j sim_ij;
// wcol_j = p_j * sum_i p_i sim_ij / rs_i + 1/rs_j  (sim symmetric).
__global__ void __launch_bounds__(256) adj_k(const float* mm, const float* E,
                                             float* wcol){
  int b = blockIdx.x;
  int tid = threadIdx.x;
  int d = tid & 63, q = tid >> 6;
  __shared__ float spp[4][64];
  __shared__ float sp[64];
  __shared__ float sE[64*129];
  __shared__ float ssim[64*65];
  __shared__ float srs[64];
  float p = 0.0f;
  for (int t = q*64; t < q*64+64; t++) p += 1.0f - mm[(b*T_ + t)*D_ + d];
  spp[q][d] = p;
  for (int i = tid; i < D_*H_; i += 256){ int r = i >> 7, c = i & 127; sE[r*129+c] = E[i]; }
  __syncthreads();
  if (tid < 64) sp[tid] = (spp[0][tid]+spp[1][tid]+spp[2][tid]+spp[3][tid]) * (1.0f/T_);
  __syncthreads();
  float rowE[128];
  #pragma unroll
  for (int k = 0; k < 128; k++) rowE[k] = sE[d*129+k];
  for (int i = q*16; i < q*16+16; i++){
    float s = 0.0f;
    #pragma unroll
    for (int k = 0; k < 128; k++) s += rowE[k]*sE[i*129+k];
    ssim[d*65+i] = fmaxf(s, 0.0f);
  }
  __syncthreads();
  if (tid < 64){
    float rs = 0.0f;
    for (int j = 0; j < 64; j++) rs += sp[j]*ssim[tid*65+j];
    srs[tid] = fmaxf(sp[tid]*rs + 1.0f, 1e-6f);
  }
  __syncthreads();
  if (tid < 64){
    float s = 0.0f;
    for (int i = 0; i < 64; i++) s += sp[i]*ssim[tid*65+i]/srs[i];
    wcol[b*64 + tid] = sp[tid]*s + 1.0f/srs[tid];
  }
}

// gi_k v6: as v5 but Phase-B weights/biases pre-scaled by LOG2E (r,z rows)
// / LOG2E2 (n rows) so gru_k's gates use bare v_exp_f32.
// Phase A: vr[32t][128h] = (x*(1-mm)*wcol/64)[32t][64d] x E[64d][128h] + time-enc
// Phase B: gi[32t][384g] = vr x (sc*W_ih)^T + sc*(bih + bhh[r,z]); gi3 [b][g][t].
#define AVP 72
#define VRP 136
#define SEP 132
__global__ void __launch_bounds__(512,1) gi_k(const float* x, const float* mm,
                                              const float* vt, const float* E,
                                              const float* wih, const float* bih,
                                              const float* bhh, const float* wcol,
                                              _Float16* gi3){
  int bid = blockIdx.x;
  int b = bid >> 3, t0 = (bid & 7)*32;
  int tid = threadIdx.x;
  int w = tid >> 6, l = tid & 63;
  int lq = l >> 4, lm = l & 15;

  __shared__ __align__(16) _Float16 av[32*AVP];
  __shared__ __align__(16) _Float16 vrA[32*VRP];
  __shared__ __align__(16) _Float16 sEl[64*SEP];
  __shared__ float sVt[32];

  // stage av[t][d] = x*(1-mm)*wcol/64  (f32 in, f16 out)
  {
    int i = tid*4, t = i >> 6, d4 = i & 63;
    long src = (long)(b*T_ + t0 + t)*D_ + d4;
    float4 xv = *(const float4*)&x[src];
    float4 mv = *(const float4*)&mm[src];
    float4 wv = *(const float4*)&wcol[b*D_ + d4];
    half4v h;
    h[0]=(_Float16)(xv.x*(1.0f-mv.x)*wv.x*(1.0f/64));
    h[1]=(_Float16)(xv.y*(1.0f-mv.y)*wv.y*(1.0f/64));
    h[2]=(_Float16)(xv.z*(1.0f-mv.z)*wv.z*(1.0f/64));
    h[3]=(_Float16)(xv.w*(1.0f-mv.w)*wv.w*(1.0f/64));
    *(half4v*)&av[t*AVP + d4] = h;
  }
  // stage E -> LDS f16, coalesced
  {
    int r = tid >> 3, c0 = (tid & 7)*16;
    #pragma unroll
    for (int g = 0; g < 4; g++){
      float4 v = *(const float4*)&E[r*H_ + c0 + g*4];
      half4v h;
      h[0]=(_Float16)v.x; h[1]=(_Float16)v.y; h[2]=(_Float16)v.z; h[3]=(_Float16)v.w;
      *(half4v*)&sEl[r*SEP + c0 + g*4] = h;
    }
  }
  if (tid < 32) sVt[tid] = vt[b*T_ + t0 + tid];
  __syncthreads();

  // Phase A B-frags: B[k=d][n] = E[d][16w+n]  (gather from LDS)
  half8 bE[2];
  #pragma unroll
  for (int kc = 0; kc < 2; kc++){
    half8 f;
    #pragma unroll
    for (int jj = 0; jj < 8; jj++)
      f[jj] = sEl[(kc*32 + lq*8 + jj)*SEP + 16*w + lm];
    bE[kc] = f;
  }

  float4v accA[2] = {{0,0,0,0},{0,0,0,0}};
  #pragma unroll
  for (int kc = 0; kc < 2; kc++){
    #pragma unroll
    for (int mt = 0; mt < 2; mt++){
      half8 a = *(const half8*)&av[(mt*16+lm)*AVP + kc*32 + lq*8];
      accA[mt] = __builtin_amdgcn_mfma_f32_16x16x32_f16(a, bE[kc], accA[mt], 0,0,0);
    }
  }
  {
    int h = 16*w + lm;
    float fr = __expf(-(float)(h & 63) * 0.14391157f);   // ln(1e4)/64
    #pragma unroll
    for (int mt = 0; mt < 2; mt++){
      #pragma unroll
      for (int r = 0; r < 4; r++){
        int tl = mt*16 + lq*4 + r;
        float ang = sVt[tl] * fr;
        float e = (h < 64) ? __sinf(ang) : __cosf(ang);
        vrA[tl*VRP + h] = (_Float16)(accA[mt][r] + e);
      }
    }
  }
  __syncthreads();

  // Phase B: wave owns N-tiles 3w..3w+2; weights/bias pre-scaled for exp2 gates
  half8 bW[3][4]; float biW[3];
  #pragma unroll
  for (int q = 0; q < 3; q++){
    int g = 16*(3*w + q) + lm;
    float sc = (g < 2*H_) ? LOG2E : LOG2E2;
    biW[q] = (bih[g] + (g < 2*H_ ? bhh[g] : 0.0f)) * sc;  // fold b_hh for r,z
    #pragma unroll
    for (int kc = 0; kc < 4; kc++){
      const float* src = &wih[(long)g*H_ + kc*32 + lq*8];
      float4 x0 = *(const float4*)src;
      float4 x1 = *(const float4*)(src+4);
      half8 f;
      f[0]=(_Float16)(x0.x*sc); f[1]=(_Float16)(x0.y*sc); f[2]=(_Float16)(x0.z*sc); f[3]=(_Float16)(x0.w*sc);
      f[4]=(_Float16)(x1.x*sc); f[5]=(_Float16)(x1.y*sc); f[6]=(_Float16)(x1.z*sc); f[7]=(_Float16)(x1.w*sc);
      bW[q][kc] = f;
    }
  }
  float4v cB[2][3];
  #pragma unroll
  for (int mt = 0; mt < 2; mt++)
    #pragma unroll
    for (int q = 0; q < 3; q++) cB[mt][q] = (float4v){0,0,0,0};
  #pragma unroll
  for (int kc = 0; kc < 4; kc++){
    #pragma unroll
    for (int mt = 0; mt < 2; mt++){
      half8 a = *(const half8*)&vrA[(mt*16+lm)*VRP + kc*32 + lq*8];
      #pragma unroll
      for (int q = 0; q < 3; q++)
        cB[mt][q] = __builtin_amdgcn_mfma_f32_16x16x32_f16(a, bW[q][kc], cB[mt][q], 0,0,0);
    }
  }
  #pragma unroll
  for (int mt = 0; mt < 2; mt++){
    #pragma unroll
    for (int q = 0; q < 3; q++){
      int g = 16*(3*w + q) + lm;
      int tb = t0 + mt*16 + lq*4;
      half4v hv;
      hv[0]=(_Float16)(cB[mt][q][0] + biW[q]); hv[1]=(_Float16)(cB[mt][q][1] + biW[q]);
      hv[2]=(_Float16)(cB[mt][q][2] + biW[q]); hv[3]=(_Float16)(cB[mt][q][3] + biW[q]);
      *(half4v*)&gi3[((long)(b*G_ + g))*T_ + tb] = hv;
    }
  }
}

// Sequential GRU v16 (R17): v10 champion skeleton (4 waves, one LDS-only BAR
// per step, chained 4-deep MFMA accumulation, f16 gi3 prefetched 8/chunk)
// with the gate chain cut: W_hh rows pre-scaled (LOG2E for r/z, LOG2E2 for n)
// at bfrag load, bn_ pre-scaled, and rcp/exp2 gate functions (no f32 div,
// no serial log2e muls). Wave w owns 6 N-tiles; gate lanes l<32 extract
// their triple via (l&16) select; h ping-pongs between two f16 LDS buffers.
__global__ void __launch_bounds__(256,1) gru_k(const _Float16* gi3, const float* whh,
                                               const float* bhh, const int* lengths,
                                               float* out){
  int b = blockIdx.x;
  int tid = threadIdx.x;
  int w = tid >> 6, l = tid & 63;
  int lq = l >> 4, lm = l & 15;
  int len = lengths[b];
  bool gate = (l < 32);
  int j = 32*w + l;              // gate index when gate==true

  __shared__ __align__(16) _Float16 hb[2][H_];

  // B-frags: tile i base {32w, 32w+16} + part*128 ; B[k][n] = sc*W_hh[nb+n][k]
  half8 bfrag[6][4];
  #pragma unroll
  for (int i = 0; i < 6; i++){
    int row = 32*w + (i>>1)*H_ + (i&1)*16 + lm;
    float sc = ((i>>1) == 2) ? LOG2E2 : LOG2E;
    #pragma unroll
    for (int kc = 0; kc < 4; kc++){
      const float* src = &whh[(long)row*H_ + kc*32 + lq*8];
      float4 x0 = *(const float4*)src;
      float4 x1 = *(const float4*)(src+4);
      half8 f;
      f[0]=(_Float16)(x0.x*sc); f[1]=(_Float16)(x0.y*sc); f[2]=(_Float16)(x0.z*sc); f[3]=(_Float16)(x0.w*sc);
      f[4]=(_Float16)(x1.x*sc); f[5]=(_Float16)(x1.y*sc); f[6]=(_Float16)(x1.z*sc); f[7]=(_Float16)(x1.w*sc);
      bfrag[i][kc] = f;
    }
  }
  float bn_ = 0.0f;
  const _Float16* pr = nullptr; const _Float16* pz; const _Float16* pn;
  if (gate){
    bn_ = bhh[2*H_ + j] * LOG2E2;
    pr = gi3 + ((long)b*G_ + j)*T_;
    pz = pr + (long)H_*T_;
    pn = pr + (long)2*H_*T_;
  }
  if (tid < H_){ hb[0][tid] = (_Float16)0.0f; hb[1][tid] = (_Float16)0.0f; }

  float gr[2][8], gz[2][8], gn[2][8];
  if (gate){
    half8 a = *(const half8*)(pr);
    half8 bv = *(const half8*)(pz);
    half8 cv = *(const half8*)(pn);
    #pragma unroll
    for (int i = 0; i < 8; i++){ gr[0][i]=(float)a[i]; gz[0][i]=(float)bv[i]; gn[0][i]=(float)cv[i]; }
  }
  __syncthreads();   // cold path: full barrier fine

  float hval = 0.0f;
  float ho[8];
  int cb = 0;
  for (int c = 0; c < 32; c++){
    if (gate && c+1 < 32){
      int nb2 = (c+1)*8;
      half8 a = *(const half8*)(pr+nb2);
      half8 bv = *(const half8*)(pz+nb2);
      half8 cv = *(const half8*)(pn+nb2);
      int nc = cb^1;
      #pragma unroll
      for (int i = 0; i < 8; i++){ gr[nc][i]=(float)a[i]; gz[nc][i]=(float)bv[i]; gn[nc][i]=(float)cv[i]; }
    }
    #pragma unroll
    for (int i = 0; i < 8; i++){
      int rp = i & 1;            // read hb[rp], write hb[rp^1]
      half8 a0v = *(const half8*)&hb[rp][0*32 + lq*8];
      half8 a1v = *(const half8*)&hb[rp][1*32 + lq*8];
      half8 a2v = *(const half8*)&hb[rp][2*32 + lq*8];
      half8 a3v = *(const half8*)&hb[rp][3*32 + lq*8];
      float4v cc[6];
      #pragma unroll
      for (int q = 0; q < 6; q++) cc[q] = (float4v){0,0,0,0};
      #pragma unroll
      for (int q = 0; q < 6; q++) cc[q] = __builtin_amdgcn_mfma_f32_16x16x32_f16(a0v, bfrag[q][0], cc[q], 0,0,0);
      #pragma unroll
      for (int q = 0; q < 6; q++) cc[q] = __builtin_amdgcn_mfma_f32_16x16x32_f16(a1v, bfrag[q][1], cc[q], 0,0,0);
      #pragma unroll
      for (int q = 0; q < 6; q++) cc[q] = __builtin_amdgcn_mfma_f32_16x16x32_f16(a2v, bfrag[q][2], cc[q], 0,0,0);
      #pragma unroll
      for (int q = 0; q < 6; q++) cc[q] = __builtin_amdgcn_mfma_f32_16x16x32_f16(a3v, bfrag[q][3], cc[q], 0,0,0);
      float ghr = (l & 16) ? cc[1][0] : cc[0][0];
      float ghz = (l & 16) ? cc[3][0] : cc[2][0];
      float ghn = (l & 16) ? cc[5][0] : cc[4][0];
      if (gate){
        float r = fsigmoid2(gr[cb][i] + ghr);
        float z = fsigmoid2(gz[cb][i] + ghz);
        float n = ftanh2(gn[cb][i] + r*(ghn + bn_));
        hval = (1.0f - z)*n + z*hval;
        hb[rp^1][j] = (_Float16)hval;
        ho[i] = (c*8 + i < len) ? hval : 0.0f;
      }
      BAR();
    }
    if (gate){
      long ob = ((long)b*T_ + c*8)*H_ + j;
      #pragma unroll
      for (int i = 0; i < 8; i++) out[ob + (long)i*H_] = ho[i];
    }
    cb ^= 1;
  }
}

extern "C" void kernel_launch(void* const* d_in, const int* in_sizes, int n_in,
                              void* d_out, int out_size, void* d_ws, size_t ws_size,
                              hipStream_t stream) {
  char* base = (char*)d_ws;
  size_t off = 0;
  auto alloc = [&](size_t bytes)->void*{
    void* p = base + off; off = (off + bytes + 255) & ~(size_t)255; return p;
  };
  float*     wcol = (float*)alloc((size_t)B_*D_*4);
  _Float16*  gi3  = (_Float16*)alloc((size_t)B_*G_*T_*2);
  if (off > ws_size) return;

  const float* x   = (const float*)d_in[0];
  const float* mm  = (const float*)d_in[1];
  const float* vt  = (const float*)d_in[2];
  const int*   len = (const int*)d_in[4];
  const float* E   = (const float*)d_in[5];
  const float* wih = (const float*)d_in[6];
  const float* whh = (const float*)d_in[7];
  const float* bih = (const float*)d_in[8];
  const float* bhh = (const float*)d_in[9];

  adj_k<<<dim3(B_),dim3(256),0,stream>>>(mm, E, wcol);
  gi_k<<<dim3(256),dim3(512),0,stream>>>(x, mm, vt, E, wih, bih, bhh, wcol, gi3);
  gru_k<<<dim3(B_),dim3(256),0,stream>>>(gi3, whh, bhh, len, (float*)d_out);
}

// Round 7
// 227.744 us; speedup vs baseline: 1.2173x; 1.0479x over previous
//
#include <hip/hip_runtime.h>
#include <hip/hip_bf16.h>

#define B_ 32
#define T_ 256
#define D_ 64
#define H_ 128
#define G_ 384   // 3*H

typedef _Float16 half8 __attribute__((ext_vector_type(8)));
typedef _Float16 half4v __attribute__((ext_vector_type(4)));
typedef float float4v __attribute__((ext_vector_type(4)));

// Fast gate functions on PRE-SCALED inputs (log2e folded into weights/biases):
// s = log2e * x          -> sigmoid(x) = 1/(1+2^-s)
// t = 2*log2e * x        -> tanh(x)    = 1 - 2/(1+2^t)
__device__ __forceinline__ float fsigmoid2(float s){
  return __builtin_amdgcn_rcpf(1.0f + __builtin_amdgcn_exp2f(-s));
}
__device__ __forceinline__ float ftanh2(float t){
  return 1.0f - 2.0f*__builtin_amdgcn_rcpf(1.0f + __builtin_amdgcn_exp2f(t));
}
#define LOG2E  1.442695041f
#define LOG2E2 2.885390082f

// NOTE (R5-R7 post-mortem): inputs/outputs are f32. bf16 misread was the NaN bug.
//
// Structure ledger (measured):
//  - v10 (R10): 4-wave 1-BAR chained-MFMA = 1241 cyc/step (132.4 us). VGPR 140.
//  - v11-v15 (R12-R16): fdot2 recurrence line, best 139.4. Allocator never
//    holds VALU-consumed weight regs resident (MFMA operands survive via
//    AGPR-parking; fdot2 operands don't). LINE CLOSED.
//  - v16 (R17): v10 + rcp/exp2 gates + log2e prefold = 1105 cyc/step
//    (117.9 us, VGPR 152, MfmaUtil 4.1). Gate-chain cut confirmed (-135 cyc).
//  - v17 (R18, this): 8-wave N-SPLIT (not R4's dup-K): 12 MFMAs/wave,
//    2 waves/SIMD interleave the matrix pipe. Tests the single-wave
//    MFMA-rate hypothesis (~32 cyc/MFMA solo -> 768 cyc of the 1105;
//    2-wave interleave -> ~466). bfrag 96->48 regs; lane-local r/z/n
//    triple (no l&16 select); unconditional gate math, guarded writes.
#define BAR() do{ asm volatile("s_waitcnt lgkmcnt(0)" ::: "memory"); \
                  __builtin_amdgcn_s_barrier(); \
                  asm volatile("" ::: "memory"); } while(0)

// wcol[b,j] = column sums of the row-normalized adjacency (R1 derivation):
// adj_raw[i,j] = p_i p_j sim_ij + I; rs_i = 1 + p_i*sum_j p_j sim_ij;
// wcol_j = p_j * sum_i p_i sim_ij / rs_i + 1/rs_j  (sim symmetric).
__global__ void __launch_bounds__(256) adj_k(const float* mm, const float* E,
                                             float* wcol){
  int b = blockIdx.x;
  int tid = threadIdx.x;
  int d = tid & 63, q = tid >> 6;
  __shared__ float spp[4][64];
  __shared__ float sp[64];
  __shared__ float sE[64*129];
  __shared__ float ssim[64*65];
  __shared__ float srs[64];
  float p = 0.0f;
  for (int t = q*64; t < q*64+64; t++) p += 1.0f - mm[(b*T_ + t)*D_ + d];
  spp[q][d] = p;
  for (int i = tid; i < D_*H_; i += 256){ int r = i >> 7, c = i & 127; sE[r*129+c] = E[i]; }
  __syncthreads();
  if (tid < 64) sp[tid] = (spp[0][tid]+spp[1][tid]+spp[2][tid]+spp[3][tid]) * (1.0f/T_);
  __syncthreads();
  float rowE[128];
  #pragma unroll
  for (int k = 0; k < 128; k++) rowE[k] = sE[d*129+k];
  for (int i = q*16; i < q*16+16; i++){
    float s = 0.0f;
    #pragma unroll
    for (int k = 0; k < 128; k++) s += rowE[k]*sE[i*129+k];
    ssim[d*65+i] = fmaxf(s, 0.0f);
  }
  __syncthreads();
  if (tid < 64){
    float rs = 0.0f;
    for (int j = 0; j < 64; j++) rs += sp[j]*ssim[tid*65+j];
    srs[tid] = fmaxf(sp[tid]*rs + 1.0f, 1e-6f);
  }
  __syncthreads();
  if (tid < 64){
    float s = 0.0f;
    for (int i = 0; i < 64; i++) s += sp[i]*ssim[tid*65+i]/srs[i];
    wcol[b*64 + tid] = sp[tid]*s + 1.0f/srs[tid];
  }
}

// gi_k v6: gi3 f16; E staged into LDS f16 (pitch 132); Phase-B weights/biases
// pre-scaled by LOG2E (r,z rows) / LOG2E2 (n rows) for exp2 gates.
// Phase A: vr[32t][128h] = (x*(1-mm)*wcol/64)[32t][64d] x E[64d][128h] + time-enc
// Phase B: gi[32t][384g] = vr x (sc*W_ih)^T + sc*(bih + bhh[r,z]); gi3 [b][g][t].
#define AVP 72
#define VRP 136
#define SEP 132
__global__ void __launch_bounds__(512,1) gi_k(const float* x, const float* mm,
                                              const float* vt, const float* E,
                                              const float* wih, const float* bih,
                                              const float* bhh, const float* wcol,
                                              _Float16* gi3){
  int bid = blockIdx.x;
  int b = bid >> 3, t0 = (bid & 7)*32;
  int tid = threadIdx.x;
  int w = tid >> 6, l = tid & 63;
  int lq = l >> 4, lm = l & 15;

  __shared__ __align__(16) _Float16 av[32*AVP];
  __shared__ __align__(16) _Float16 vrA[32*VRP];
  __shared__ __align__(16) _Float16 sEl[64*SEP];
  __shared__ float sVt[32];

  // stage av[t][d] = x*(1-mm)*wcol/64  (f32 in, f16 out)
  {
    int i = tid*4, t = i >> 6, d4 = i & 63;
    long src = (long)(b*T_ + t0 + t)*D_ + d4;
    float4 xv = *(const float4*)&x[src];
    float4 mv = *(const float4*)&mm[src];
    float4 wv = *(const float4*)&wcol[b*D_ + d4];
    half4v h;
    h[0]=(_Float16)(xv.x*(1.0f-mv.x)*wv.x*(1.0f/64));
    h[1]=(_Float16)(xv.y*(1.0f-mv.y)*wv.y*(1.0f/64));
    h[2]=(_Float16)(xv.z*(1.0f-mv.z)*wv.z*(1.0f/64));
    h[3]=(_Float16)(xv.w*(1.0f-mv.w)*wv.w*(1.0f/64));
    *(half4v*)&av[t*AVP + d4] = h;
  }
  // stage E -> LDS f16, coalesced
  {
    int r = tid >> 3, c0 = (tid & 7)*16;
    #pragma unroll
    for (int g = 0; g < 4; g++){
      float4 v = *(const float4*)&E[r*H_ + c0 + g*4];
      half4v h;
      h[0]=(_Float16)v.x; h[1]=(_Float16)v.y; h[2]=(_Float16)v.z; h[3]=(_Float16)v.w;
      *(half4v*)&sEl[r*SEP + c0 + g*4] = h;
    }
  }
  if (tid < 32) sVt[tid] = vt[b*T_ + t0 + tid];
  __syncthreads();

  // Phase A B-frags: B[k=d][n] = E[d][16w+n]  (gather from LDS)
  half8 bE[2];
  #pragma unroll
  for (int kc = 0; kc < 2; kc++){
    half8 f;
    #pragma unroll
    for (int jj = 0; jj < 8; jj++)
      f[jj] = sEl[(kc*32 + lq*8 + jj)*SEP + 16*w + lm];
    bE[kc] = f;
  }

  float4v accA[2] = {{0,0,0,0},{0,0,0,0}};
  #pragma unroll
  for (int kc = 0; kc < 2; kc++){
    #pragma unroll
    for (int mt = 0; mt < 2; mt++){
      half8 a = *(const half8*)&av[(mt*16+lm)*AVP + kc*32 + lq*8];
      accA[mt] = __builtin_amdgcn_mfma_f32_16x16x32_f16(a, bE[kc], accA[mt], 0,0,0);
    }
  }
  {
    int h = 16*w + lm;
    float fr = __expf(-(float)(h & 63) * 0.14391157f);   // ln(1e4)/64
    #pragma unroll
    for (int mt = 0; mt < 2; mt++){
      #pragma unroll
      for (int r = 0; r < 4; r++){
        int tl = mt*16 + lq*4 + r;
        float ang = sVt[tl] * fr;
        float e = (h < 64) ? __sinf(ang) : __cosf(ang);
        vrA[tl*VRP + h] = (_Float16)(accA[mt][r] + e);
      }
    }
  }
  __syncthreads();

  // Phase B: wave owns N-tiles 3w..3w+2; weights/bias pre-scaled for exp2 gates
  half8 bW[3][4]; float biW[3];
  #pragma unroll
  for (int q = 0; q < 3; q++){
    int g = 16*(3*w + q) + lm;
    float sc = (g < 2*H_) ? LOG2E : LOG2E2;
    biW[q] = (bih[g] + (g < 2*H_ ? bhh[g] : 0.0f)) * sc;  // fold b_hh for r,z
    #pragma unroll
    for (int kc = 0; kc < 4; kc++){
      const float* src = &wih[(long)g*H_ + kc*32 + lq*8];
      float4 x0 = *(const float4*)src;
      float4 x1 = *(const float4*)(src+4);
      half8 f;
      f[0]=(_Float16)(x0.x*sc); f[1]=(_Float16)(x0.y*sc); f[2]=(_Float16)(x0.z*sc); f[3]=(_Float16)(x0.w*sc);
      f[4]=(_Float16)(x1.x*sc); f[5]=(_Float16)(x1.y*sc); f[6]=(_Float16)(x1.z*sc); f[7]=(_Float16)(x1.w*sc);
      bW[q][kc] = f;
    }
  }
  float4v cB[2][3];
  #pragma unroll
  for (int mt = 0; mt < 2; mt++)
    #pragma unroll
    for (int q = 0; q < 3; q++) cB[mt][q] = (float4v){0,0,0,0};
  #pragma unroll
  for (int kc = 0; kc < 4; kc++){
    #pragma unroll
    for (int mt = 0; mt < 2; mt++){
      half8 a = *(const half8*)&vrA[(mt*16+lm)*VRP + kc*32 + lq*8];
      #pragma unroll
      for (int q = 0; q < 3; q++)
        cB[mt][q] = __builtin_amdgcn_mfma_f32_16x16x32_f16(a, bW[q][kc], cB[mt][q], 0,0,0);
    }
  }
  #pragma unroll
  for (int mt = 0; mt < 2; mt++){
    #pragma unroll
    for (int q = 0; q < 3; q++){
      int g = 16*(3*w + q) + lm;
      int tb = t0 + mt*16 + lq*4;
      half4v hv;
      hv[0]=(_Float16)(cB[mt][q][0] + biW[q]); hv[1]=(_Float16)(cB[mt][q][1] + biW[q]);
      hv[2]=(_Float16)(cB[mt][q][2] + biW[q]); hv[3]=(_Float16)(cB[mt][q][3] + biW[q]);
      *(half4v*)&gi3[((long)(b*G_ + g))*T_ + tb] = hv;
    }
  }
}

// Sequential GRU v17 (R18): 8-wave N-split, 12 MFMAs/wave, 2 waves/SIMD.
// Wave w owns gates j in [16w, 16w+16): three chains (r,z,n rows of W_hh,
// pre-scaled LOG2E/LOG2E2), depth-4 over k-chunks. Lane l<16 holds the
// full (r,z,n) triple for gate j=16w+l in (c0,c1,c2)[0] -> no cross-tile
// select. Gate math unconditional (garbage on l>=16, never written);
// LDS h-write + out guarded. One LDS-only BAR per step, hb[2] f16
// ping-pong, named A/B gi prefetch regs with lazy f16->f32 cvt.
__global__ void __launch_bounds__(512,1) gru_k(const _Float16* gi3, const float* whh,
                                               const float* bhh, const int* lengths,
                                               float* out){
  int b = blockIdx.x;
  int tid = threadIdx.x;
  int w = tid >> 6, l = tid & 63;
  int lq = l >> 4;
  int j = 16*w + (l & 15);       // gate dim owned (valid for all lanes)
  bool gate = (l < 16);
  int len = lengths[b];

  __shared__ __align__(16) _Float16 hb[2][H_];

  // B-frags: q=0 r, 1 z, 2 n ; B[k][n] = sc*W_hh[q*H + 16w + n][k]
  half8 bfrag[3][4];
  #pragma unroll
  for (int q = 0; q < 3; q++){
    int row = q*H_ + 16*w + (l & 15);
    float sc = (q == 2) ? LOG2E2 : LOG2E;
    #pragma unroll
    for (int kc = 0; kc < 4; kc++){
      const float* src = &whh[(long)row*H_ + kc*32 + lq*8];
      float4 x0 = *(const float4*)src;
      float4 x1 = *(const float4*)(src+4);
      half8 f;
      f[0]=(_Float16)(x0.x*sc); f[1]=(_Float16)(x0.y*sc); f[2]=(_Float16)(x0.z*sc); f[3]=(_Float16)(x0.w*sc);
      f[4]=(_Float16)(x1.x*sc); f[5]=(_Float16)(x1.y*sc); f[6]=(_Float16)(x1.z*sc); f[7]=(_Float16)(x1.w*sc);
      bfrag[q][kc] = f;
    }
  }
  float bn_ = bhh[2*H_ + j] * LOG2E2;
  const _Float16* pr = gi3 + ((long)b*G_ + j)*T_;
  const _Float16* pz = pr + (long)H_*T_;
  const _Float16* pn = pr + (long)2*H_*T_;

  if (tid < H_){ hb[0][tid] = (_Float16)0.0f; hb[1][tid] = (_Float16)0.0f; }

  // gi prefetch: named double-buffer registers, static indexing only
  half8 prA, pzA, pnA, prB, pzB, pnB;
  prA = *(const half8*)pr; pzA = *(const half8*)pz; pnA = *(const half8*)pn;
  __syncthreads();   // cold path: full barrier fine

  float hval = 0.0f;

  auto substeps = [&](half8 cr, half8 cz, half8 cn, int c){
    float ho[8];
    #pragma unroll
    for (int i = 0; i < 8; i++){
      const int rp = i & 1;            // read hb[rp], write hb[rp^1]
      half8 a0v = *(const half8*)&hb[rp][ 0 + lq*8];
      half8 a1v = *(const half8*)&hb[rp][32 + lq*8];
      half8 a2v = *(const half8*)&hb[rp][64 + lq*8];
      half8 a3v = *(const half8*)&hb[rp][96 + lq*8];
      float4v c0 = {0,0,0,0}, c1 = {0,0,0,0}, c2 = {0,0,0,0};
      c0 = __builtin_amdgcn_mfma_f32_16x16x32_f16(a0v, bfrag[0][0], c0, 0,0,0);
      c1 = __builtin_amdgcn_mfma_f32_16x16x32_f16(a0v, bfrag[1][0], c1, 0,0,0);
      c2 = __builtin_amdgcn_mfma_f32_16x16x32_f16(a0v, bfrag[2][0], c2, 0,0,0);
      c0 = __builtin_amdgcn_mfma_f32_16x16x32_f16(a1v, bfrag[0][1], c0, 0,0,0);
      c1 = __builtin_amdgcn_mfma_f32_16x16x32_f16(a1v, bfrag[1][1], c1, 0,0,0);
      c2 = __builtin_amdgcn_mfma_f32_16x16x32_f16(a1v, bfrag[2][1], c2, 0,0,0);
      c0 = __builtin_amdgcn_mfma_f32_16x16x32_f16(a2v, bfrag[0][2], c0, 0,0,0);
      c1 = __builtin_amdgcn_mfma_f32_16x16x32_f16(a2v, bfrag[1][2], c1, 0,0,0);
      c2 = __builtin_amdgcn_mfma_f32_16x16x32_f16(a2v, bfrag[2][2], c2, 0,0,0);
      c0 = __builtin_amdgcn_mfma_f32_16x16x32_f16(a3v, bfrag[0][3], c0, 0,0,0);
      c1 = __builtin_amdgcn_mfma_f32_16x16x32_f16(a3v, bfrag[1][3], c1, 0,0,0);
      c2 = __builtin_amdgcn_mfma_f32_16x16x32_f16(a3v, bfrag[2][3], c2, 0,0,0);
      float r = fsigmoid2((float)cr[i] + c0[0]);
      float z = fsigmoid2((float)cz[i] + c1[0]);
      float n = ftanh2((float)cn[i] + r*(c2[0] + bn_));
      hval = (1.0f - z)*n + z*hval;
      if (gate){
        hb[rp^1][j] = (_Float16)hval;
        ho[i] = (c*8 + i < len) ? hval : 0.0f;
      }
      BAR();
    }
    if (gate){
      long ob = ((long)b*T_ + c*8)*H_ + j;
      #pragma unroll
      for (int i = 0; i < 8; i++) out[ob + (long)i*H_] = ho[i];
    }
  };

  for (int c = 0; c < 32; c += 2){
    {
      int nb = (c+1)*8;
      prB = *(const half8*)(pr+nb); pzB = *(const half8*)(pz+nb); pnB = *(const half8*)(pn+nb);
    }
    substeps(prA, pzA, pnA, c);
    if (c+2 < 32){
      int nb = (c+2)*8;
      prA = *(const half8*)(pr+nb); pzA = *(const half8*)(pz+nb); pnA = *(const half8*)(pn+nb);
    }
    substeps(prB, pzB, pnB, c+1);
  }
}

extern "C" void kernel_launch(void* const* d_in, const int* in_sizes, int n_in,
                              void* d_out, int out_size, void* d_ws, size_t ws_size,
                              hipStream_t stream) {
  char* base = (char*)d_ws;
  size_t off = 0;
  auto alloc = [&](size_t bytes)->void*{
    void* p = base + off; off = (off + bytes + 255) & ~(size_t)255; return p;
  };
  float*     wcol = (float*)alloc((size_t)B_*D_*4);
  _Float16*  gi3  = (_Float16*)alloc((size_t)B_*G_*T_*2);
  if (off > ws_size) return;

  const float* x   = (const float*)d_in[0];
  const float* mm  = (const float*)d_in[1];
  const float* vt  = (const float*)d_in[2];
  const int*   len = (const int*)d_in[4];
  const float* E   = (const float*)d_in[5];
  const float* wih = (const float*)d_in[6];
  const float* whh = (const float*)d_in[7];
  const float* bih = (const float*)d_in[8];
  const float* bhh = (const float*)d_in[9];

  adj_k<<<dim3(B_),dim3(256),0,stream>>>(mm, E, wcol);
  gi_k<<<dim3(256),dim3(512),0,stream>>>(x, mm, vt, E, wih, bih, bhh, wcol, gi3);
  gru_k<<<dim3(B_),dim3(512),0,stream>>>(gi3, whh, bhh, len, (float*)d_out);
}

// Round 8
// 224.426 us; speedup vs baseline: 1.2353x; 1.0148x over previous
//
#include <hip/hip_runtime.h>
#include <hip/hip_bf16.h>

#define B_ 32
#define T_ 256
#define D_ 64
#define H_ 128
#define G_ 384   // 3*H

typedef _Float16 half8 __attribute__((ext_vector_type(8)));
typedef _Float16 half4v __attribute__((ext_vector_type(4)));
typedef float float4v __attribute__((ext_vector_type(4)));

// Fast gate functions on PRE-SCALED inputs (log2e folded into weights/biases):
// s = log2e * x          -> sigmoid(x) = 1/(1+2^-s)
// t = 2*log2e * x        -> tanh(x)    = 1 - 2/(1+2^t)
__device__ __forceinline__ float fsigmoid2(float s){
  return __builtin_amdgcn_rcpf(1.0f + __builtin_amdgcn_exp2f(-s));
}
__device__ __forceinline__ float ftanh2(float t){
  return 1.0f - 2.0f*__builtin_amdgcn_rcpf(1.0f + __builtin_amdgcn_exp2f(t));
}
#define LOG2E  1.442695041f
#define LOG2E2 2.885390082f

// NOTE (R5-R7 post-mortem): inputs/outputs are f32. bf16 misread was the NaN bug.
//
// Structure ledger (measured):
//  - v10 (R10): 4-wave 1-BAR chained-MFMA = 1241 cyc/step (132.4 us).
//  - v11-v15 (R12-R16): fdot2 line closed (allocator remat/spill; best 139.4).
//  - v16 (R17): rcp/exp2 gates + log2e prefold = 1105 cyc/step (117.9 us).
//  - v17 (R18): 8-wave N-split, 12 MFMA/wave, 2 waves/SIMD = ~990 cyc/step
//    (105.7 us, VGPR 60). Interleave hides ~115 cyc of serial work.
//    Per-CU MFMA pipe floor: 96 MFMA x 4.85 cyc = 466 cyc/step (invariant:
//    M-packing batches shares pipe, doesn't cut step latency).
//  - v18 (R19, this): depth-2 split MFMA chains (6 chains + 3 adds; -2 MFMA
//    latencies off critical path), setprio(1) around MFMA cluster, and
//    waves_per_eu(2,2) (truthful; v17's VGPR=60 = allocator throttled for
//    phantom 8-wave occupancy). Non-gru residue (~121 us) is harness
//    re-poison dispatches, not kernel time — gru_k is the only lever.
#define BAR() do{ asm volatile("s_waitcnt lgkmcnt(0)" ::: "memory"); \
                  __builtin_amdgcn_s_barrier(); \
                  asm volatile("" ::: "memory"); } while(0)

// wcol[b,j] = column sums of the row-normalized adjacency (R1 derivation):
// adj_raw[i,j] = p_i p_j sim_ij + I; rs_i = 1 + p_i*sum_j p_j sim_ij;
// wcol_j = p_j * sum_i p_i sim_ij / rs_i + 1/rs_j  (sim symmetric).
__global__ void __launch_bounds__(256) adj_k(const float* mm, const float* E,
                                             float* wcol){
  int b = blockIdx.x;
  int tid = threadIdx.x;
  int d = tid & 63, q = tid >> 6;
  __shared__ float spp[4][64];
  __shared__ float sp[64];
  __shared__ float sE[64*129];
  __shared__ float ssim[64*65];
  __shared__ float srs[64];
  float p = 0.0f;
  for (int t = q*64; t < q*64+64; t++) p += 1.0f - mm[(b*T_ + t)*D_ + d];
  spp[q][d] = p;
  for (int i = tid; i < D_*H_; i += 256){ int r = i >> 7, c = i & 127; sE[r*129+c] = E[i]; }
  __syncthreads();
  if (tid < 64) sp[tid] = (spp[0][tid]+spp[1][tid]+spp[2][tid]+spp[3][tid]) * (1.0f/T_);
  __syncthreads();
  float rowE[128];
  #pragma unroll
  for (int k = 0; k < 128; k++) rowE[k] = sE[d*129+k];
  for (int i = q*16; i < q*16+16; i++){
    float s = 0.0f;
    #pragma unroll
    for (int k = 0; k < 128; k++) s += rowE[k]*sE[i*129+k];
    ssim[d*65+i] = fmaxf(s, 0.0f);
  }
  __syncthreads();
  if (tid < 64){
    float rs = 0.0f;
    for (int j = 0; j < 64; j++) rs += sp[j]*ssim[tid*65+j];
    srs[tid] = fmaxf(sp[tid]*rs + 1.0f, 1e-6f);
  }
  __syncthreads();
  if (tid < 64){
    float s = 0.0f;
    for (int i = 0; i < 64; i++) s += sp[i]*ssim[tid*65+i]/srs[i];
    wcol[b*64 + tid] = sp[tid]*s + 1.0f/srs[tid];
  }
}

// gi_k v6: gi3 f16; E staged into LDS f16 (pitch 132); Phase-B weights/biases
// pre-scaled by LOG2E (r,z rows) / LOG2E2 (n rows) for exp2 gates.
// Phase A: vr[32t][128h] = (x*(1-mm)*wcol/64)[32t][64d] x E[64d][128h] + time-enc
// Phase B: gi[32t][384g] = vr x (sc*W_ih)^T + sc*(bih + bhh[r,z]); gi3 [b][g][t].
#define AVP 72
#define VRP 136
#define SEP 132
__global__ void __launch_bounds__(512,1) gi_k(const float* x, const float* mm,
                                              const float* vt, const float* E,
                                              const float* wih, const float* bih,
                                              const float* bhh, const float* wcol,
                                              _Float16* gi3){
  int bid = blockIdx.x;
  int b = bid >> 3, t0 = (bid & 7)*32;
  int tid = threadIdx.x;
  int w = tid >> 6, l = tid & 63;
  int lq = l >> 4, lm = l & 15;

  __shared__ __align__(16) _Float16 av[32*AVP];
  __shared__ __align__(16) _Float16 vrA[32*VRP];
  __shared__ __align__(16) _Float16 sEl[64*SEP];
  __shared__ float sVt[32];

  // stage av[t][d] = x*(1-mm)*wcol/64  (f32 in, f16 out)
  {
    int i = tid*4, t = i >> 6, d4 = i & 63;
    long src = (long)(b*T_ + t0 + t)*D_ + d4;
    float4 xv = *(const float4*)&x[src];
    float4 mv = *(const float4*)&mm[src];
    float4 wv = *(const float4*)&wcol[b*D_ + d4];
    half4v h;
    h[0]=(_Float16)(xv.x*(1.0f-mv.x)*wv.x*(1.0f/64));
    h[1]=(_Float16)(xv.y*(1.0f-mv.y)*wv.y*(1.0f/64));
    h[2]=(_Float16)(xv.z*(1.0f-mv.z)*wv.z*(1.0f/64));
    h[3]=(_Float16)(xv.w*(1.0f-mv.w)*wv.w*(1.0f/64));
    *(half4v*)&av[t*AVP + d4] = h;
  }
  // stage E -> LDS f16, coalesced
  {
    int r = tid >> 3, c0 = (tid & 7)*16;
    #pragma unroll
    for (int g = 0; g < 4; g++){
      float4 v = *(const float4*)&E[r*H_ + c0 + g*4];
      half4v h;
      h[0]=(_Float16)v.x; h[1]=(_Float16)v.y; h[2]=(_Float16)v.z; h[3]=(_Float16)v.w;
      *(half4v*)&sEl[r*SEP + c0 + g*4] = h;
    }
  }
  if (tid < 32) sVt[tid] = vt[b*T_ + t0 + tid];
  __syncthreads();

  // Phase A B-frags: B[k=d][n] = E[d][16w+n]  (gather from LDS)
  half8 bE[2];
  #pragma unroll
  for (int kc = 0; kc < 2; kc++){
    half8 f;
    #pragma unroll
    for (int jj = 0; jj < 8; jj++)
      f[jj] = sEl[(kc*32 + lq*8 + jj)*SEP + 16*w + lm];
    bE[kc] = f;
  }

  float4v accA[2] = {{0,0,0,0},{0,0,0,0}};
  #pragma unroll
  for (int kc = 0; kc < 2; kc++){
    #pragma unroll
    for (int mt = 0; mt < 2; mt++){
      half8 a = *(const half8*)&av[(mt*16+lm)*AVP + kc*32 + lq*8];
      accA[mt] = __builtin_amdgcn_mfma_f32_16x16x32_f16(a, bE[kc], accA[mt], 0,0,0);
    }
  }
  {
    int h = 16*w + lm;
    float fr = __expf(-(float)(h & 63) * 0.14391157f);   // ln(1e4)/64
    #pragma unroll
    for (int mt = 0; mt < 2; mt++){
      #pragma unroll
      for (int r = 0; r < 4; r++){
        int tl = mt*16 + lq*4 + r;
        float ang = sVt[tl] * fr;
        float e = (h < 64) ? __sinf(ang) : __cosf(ang);
        vrA[tl*VRP + h] = (_Float16)(accA[mt][r] + e);
      }
    }
  }
  __syncthreads();

  // Phase B: wave owns N-tiles 3w..3w+2; weights/bias pre-scaled for exp2 gates
  half8 bW[3][4]; float biW[3];
  #pragma unroll
  for (int q = 0; q < 3; q++){
    int g = 16*(3*w + q) + lm;
    float sc = (g < 2*H_) ? LOG2E : LOG2E2;
    biW[q] = (bih[g] + (g < 2*H_ ? bhh[g] : 0.0f)) * sc;  // fold b_hh for r,z
    #pragma unroll
    for (int kc = 0; kc < 4; kc++){
      const float* src = &wih[(long)g*H_ + kc*32 + lq*8];
      float4 x0 = *(const float4*)src;
      float4 x1 = *(const float4*)(src+4);
      half8 f;
      f[0]=(_Float16)(x0.x*sc); f[1]=(_Float16)(x0.y*sc); f[2]=(_Float16)(x0.z*sc); f[3]=(_Float16)(x0.w*sc);
      f[4]=(_Float16)(x1.x*sc); f[5]=(_Float16)(x1.y*sc); f[6]=(_Float16)(x1.z*sc); f[7]=(_Float16)(x1.w*sc);
      bW[q][kc] = f;
    }
  }
  float4v cB[2][3];
  #pragma unroll
  for (int mt = 0; mt < 2; mt++)
    #pragma unroll
    for (int q = 0; q < 3; q++) cB[mt][q] = (float4v){0,0,0,0};
  #pragma unroll
  for (int kc = 0; kc < 4; kc++){
    #pragma unroll
    for (int mt = 0; mt < 2; mt++){
      half8 a = *(const half8*)&vrA[(mt*16+lm)*VRP + kc*32 + lq*8];
      #pragma unroll
      for (int q = 0; q < 3; q++)
        cB[mt][q] = __builtin_amdgcn_mfma_f32_16x16x32_f16(a, bW[q][kc], cB[mt][q], 0,0,0);
    }
  }
  #pragma unroll
  for (int mt = 0; mt < 2; mt++){
    #pragma unroll
    for (int q = 0; q < 3; q++){
      int g = 16*(3*w + q) + lm;
      int tb = t0 + mt*16 + lq*4;
      half4v hv;
      hv[0]=(_Float16)(cB[mt][q][0] + biW[q]); hv[1]=(_Float16)(cB[mt][q][1] + biW[q]);
      hv[2]=(_Float16)(cB[mt][q][2] + biW[q]); hv[3]=(_Float16)(cB[mt][q][3] + biW[q]);
      *(half4v*)&gi3[((long)(b*G_ + g))*T_ + tb] = hv;
    }
  }
}

// Sequential GRU v18 (R19): 8-wave N-split with depth-2 split MFMA chains.
// Wave w owns gates j in [16w, 16w+16): per gate-part (r,z,n) TWO depth-2
// chains (a0/a1 -> c*a, a2/a3 -> c*b) summed by one VALU add — same 12
// MFMA issues, ~2 MFMA latencies shorter critical path, c*b chains start
// as soon as a2v/a3v land. setprio(1) wraps the MFMA cluster (2 waves/SIMD
// role-stagger). waves_per_eu(2,2) truthful clamp (1 block/CU x 8 waves)
// lifts the allocator's phantom-occupancy VGPR throttle (v17: VGPR 60).
// Gate math unconditional; LDS h-write + out guarded. One LDS-only BAR
// per step, hb[2] f16 ping-pong, named A/B gi prefetch regs.
__global__ void __attribute__((amdgpu_waves_per_eu(2, 2)))
__launch_bounds__(512) gru_k(const _Float16* gi3, const float* whh,
                             const float* bhh, const int* lengths,
                             float* out){
  int b = blockIdx.x;
  int tid = threadIdx.x;
  int w = tid >> 6, l = tid & 63;
  int lq = l >> 4;
  int j = 16*w + (l & 15);       // gate dim owned (valid for all lanes)
  bool gate = (l < 16);
  int len = lengths[b];

  __shared__ __align__(16) _Float16 hb[2][H_];

  // B-frags: q=0 r, 1 z, 2 n ; B[k][n] = sc*W_hh[q*H + 16w + n][k]
  half8 bfrag[3][4];
  #pragma unroll
  for (int q = 0; q < 3; q++){
    int row = q*H_ + 16*w + (l & 15);
    float sc = (q == 2) ? LOG2E2 : LOG2E;
    #pragma unroll
    for (int kc = 0; kc < 4; kc++){
      const float* src = &whh[(long)row*H_ + kc*32 + lq*8];
      float4 x0 = *(const float4*)src;
      float4 x1 = *(const float4*)(src+4);
      half8 f;
      f[0]=(_Float16)(x0.x*sc); f[1]=(_Float16)(x0.y*sc); f[2]=(_Float16)(x0.z*sc); f[3]=(_Float16)(x0.w*sc);
      f[4]=(_Float16)(x1.x*sc); f[5]=(_Float16)(x1.y*sc); f[6]=(_Float16)(x1.z*sc); f[7]=(_Float16)(x1.w*sc);
      bfrag[q][kc] = f;
    }
  }
  float bn_ = bhh[2*H_ + j] * LOG2E2;
  const _Float16* pr = gi3 + ((long)b*G_ + j)*T_;
  const _Float16* pz = pr + (long)H_*T_;
  const _Float16* pn = pr + (long)2*H_*T_;

  if (tid < H_){ hb[0][tid] = (_Float16)0.0f; hb[1][tid] = (_Float16)0.0f; }

  // gi prefetch: named double-buffer registers, static indexing only
  half8 prA, pzA, pnA, prB, pzB, pnB;
  prA = *(const half8*)pr; pzA = *(const half8*)pz; pnA = *(const half8*)pn;
  __syncthreads();   // cold path: full barrier fine

  float hval = 0.0f;

  auto substeps = [&](half8 cr, half8 cz, half8 cn, int c){
    float ho[8];
    #pragma unroll
    for (int i = 0; i < 8; i++){
      const int rp = i & 1;            // read hb[rp], write hb[rp^1]
      half8 a0v = *(const half8*)&hb[rp][ 0 + lq*8];
      half8 a1v = *(const half8*)&hb[rp][32 + lq*8];
      half8 a2v = *(const half8*)&hb[rp][64 + lq*8];
      half8 a3v = *(const half8*)&hb[rp][96 + lq*8];
      float4v c0a = {0,0,0,0}, c1a = {0,0,0,0}, c2a = {0,0,0,0};
      float4v c0b = {0,0,0,0}, c1b = {0,0,0,0}, c2b = {0,0,0,0};
      __builtin_amdgcn_s_setprio(1);
      c0a = __builtin_amdgcn_mfma_f32_16x16x32_f16(a0v, bfrag[0][0], c0a, 0,0,0);
      c1a = __builtin_amdgcn_mfma_f32_16x16x32_f16(a0v, bfrag[1][0], c1a, 0,0,0);
      c2a = __builtin_amdgcn_mfma_f32_16x16x32_f16(a0v, bfrag[2][0], c2a, 0,0,0);
      c0b = __builtin_amdgcn_mfma_f32_16x16x32_f16(a2v, bfrag[0][2], c0b, 0,0,0);
      c1b = __builtin_amdgcn_mfma_f32_16x16x32_f16(a2v, bfrag[1][2], c1b, 0,0,0);
      c2b = __builtin_amdgcn_mfma_f32_16x16x32_f16(a2v, bfrag[2][2], c2b, 0,0,0);
      c0a = __builtin_amdgcn_mfma_f32_16x16x32_f16(a1v, bfrag[0][1], c0a, 0,0,0);
      c1a = __builtin_amdgcn_mfma_f32_16x16x32_f16(a1v, bfrag[1][1], c1a, 0,0,0);
      c2a = __builtin_amdgcn_mfma_f32_16x16x32_f16(a1v, bfrag[2][1], c2a, 0,0,0);
      c0b = __builtin_amdgcn_mfma_f32_16x16x32_f16(a3v, bfrag[0][3], c0b, 0,0,0);
      c1b = __builtin_amdgcn_mfma_f32_16x16x32_f16(a3v, bfrag[1][3], c1b, 0,0,0);
      c2b = __builtin_amdgcn_mfma_f32_16x16x32_f16(a3v, bfrag[2][3], c2b, 0,0,0);
      __builtin_amdgcn_s_setprio(0);
      float ghr = c0a[0] + c0b[0];
      float ghz = c1a[0] + c1b[0];
      float ghn = c2a[0] + c2b[0];
      float r = fsigmoid2((float)cr[i] + ghr);
      float z = fsigmoid2((float)cz[i] + ghz);
      float n = ftanh2((float)cn[i] + r*(ghn + bn_));
      hval = (1.0f - z)*n + z*hval;
      if (gate){
        hb[rp^1][j] = (_Float16)hval;
        ho[i] = (c*8 + i < len) ? hval : 0.0f;
      }
      BAR();
    }
    if (gate){
      long ob = ((long)b*T_ + c*8)*H_ + j;
      #pragma unroll
      for (int i = 0; i < 8; i++) out[ob + (long)i*H_] = ho[i];
    }
  };

  for (int c = 0; c < 32; c += 2){
    {
      int nb = (c+1)*8;
      prB = *(const half8*)(pr+nb); pzB = *(const half8*)(pz+nb); pnB = *(const half8*)(pn+nb);
    }
    substeps(prA, pzA, pnA, c);
    if (c+2 < 32){
      int nb = (c+2)*8;
      prA = *(const half8*)(pr+nb); pzA = *(const half8*)(pz+nb); pnA = *(const half8*)(pn+nb);
    }
    substeps(prB, pzB, pnB, c+1);
  }
}

extern "C" void kernel_launch(void* const* d_in, const int* in_sizes, int n_in,
                              void* d_out, int out_size, void* d_ws, size_t ws_size,
                              hipStream_t stream) {
  char* base = (char*)d_ws;
  size_t off = 0;
  auto alloc = [&](size_t bytes)->void*{
    void* p = base + off; off = (off + bytes + 255) & ~(size_t)255; return p;
  };
  float*     wcol = (float*)alloc((size_t)B_*D_*4);
  _Float16*  gi3  = (_Float16*)alloc((size_t)B_*G_*T_*2);
  if (off > ws_size) return;

  const float* x   = (const float*)d_in[0];
  const float* mm  = (const float*)d_in[1];
  const float* vt  = (const float*)d_in[2];
  const int*   len = (const int*)d_in[4];
  const float* E   = (const float*)d_in[5];
  const float* wih = (const float*)d_in[6];
  const float* whh = (const float*)d_in[7];
  const float* bih = (const float*)d_in[8];
  const float* bhh = (const float*)d_in[9];

  adj_k<<<dim3(B_),dim3(256),0,stream>>>(mm, E, wcol);
  gi_k<<<dim3(256),dim3(512),0,stream>>>(x, mm, vt, E, wih, bih, bhh, wcol, gi3);
  gru_k<<<dim3(B_),dim3(512),0,stream>>>(gi3, whh, bhh, len, (float*)d_out);
}